// Round 11
// baseline (571.245 us; speedup 1.0000x reference)
//
#include <hip/hip_runtime.h>
#include <hip/hip_bf16.h>
#include <math.h>

#define N_PTS 8192
#define QPW 4                 // queries per wave
#define WPB 4                 // waves per block
#define QPB (QPW * WPB)       // 16 queries per block
#define BLKS_PER_PASS (N_PTS / QPB)   // 512

#define NB 256                // z bins (counting sort)
#define NCH 128               // chunks of 64 per set
#define ZMINF (-6.0f)
#define ZW 0.046875f          // 12/256
#define INV_ZW (1.0f / ZW)

#define HW_SELF 13            // half-window (chunks) for K=10 self-kNN
#define HW_CROSS 11           // for K=5 cross (center located via bin prefix, +-3 slop)
#define HW_REV 7              // for 1-NN

// F_CHAMFER*ALPHA0 = 0.02, F_CURVATURE*ALPHA0 = 0.006, F_SMOOTH*ALPHA0 = 0.01
#define W_CHAM 0.02f
#define W_CURV 0.006f
#define W_SMOO 0.01f

#define BIGF 1e30f

__device__ __forceinline__ int zbin(float z) {
    int b = (int)floorf((z - ZMINF) * INV_ZW);
    return min(max(b, 0), NB - 1);
}

// ---- wave-uniform sorted insert (fallback path only) ----
template <int K>
__device__ __forceinline__ void uinsert(float d, int idx, float (&bd)[K], int (&bi)[K]) {
    bd[K - 1] = d; bi[K - 1] = idx;
#pragma unroll
    for (int s = K - 1; s > 0; --s) {
        bool sw = bd[s] < bd[s - 1];
        float td = sw ? bd[s - 1] : bd[s];
        bd[s - 1] = sw ? bd[s] : bd[s - 1];
        bd[s] = td;
        int ti = sw ? bi[s - 1] : bi[s];
        bi[s - 1] = sw ? bi[s] : bi[s - 1];
        bi[s] = ti;
    }
}

// ---- merge 64 per-lane sorted lists {(m1,i1),(m2,i2),(m3,-)} -> global top-K ----
template <int K>
__device__ __forceinline__ void merge_pop(float m1, float m2, float m3, int i1, int i2,
                                          float (&bd)[K], int (&bi)[K], int lane) {
    float h0 = m1, h1 = m2, h2 = m3;
    int   j0 = i1, j1 = i2;
#pragma unroll
    for (int r = 0; r < K; ++r) {
        float bv = h0;
#pragma unroll
        for (int off = 1; off < 64; off <<= 1) bv = fminf(bv, __shfl_xor(bv, off));
        unsigned long long eq = __ballot(h0 == bv);
        int wl = (int)__builtin_ctzll(eq);
        bd[r] = bv; bi[r] = __shfl(j0, wl);
        if (lane == wl) { h0 = h1; j0 = j1; h1 = h2; j1 = -1; h2 = BIGF; }
    }
}

// ---- exact fixed-tau FULL rescan (shifted domain); tau = window kth (upper bd) ----
template <int K>
__device__ void tau_rescan(const float4* __restrict__ cand,
                           float qx, float qy, float qz, float tau,
                           float (&bd)[K], int (&bi)[K], int lane) {
#pragma unroll
    for (int r = 0; r < K; ++r) { bd[r] = BIGF; bi[r] = 0; }
    const float4* cp = cand + lane;
    for (int it = 0; it < N_PTS / 64; ++it) {
        float4 p = cp[it * 64];
        float dot = fmaf(p.x, qx, fmaf(p.y, qy, p.z * qz));
        float d = fmaf(-2.f, dot, p.w);
        unsigned long long m = __ballot(d <= tau);
        while (m) {
            int b = __builtin_ctzll(m);
            m &= m - 1;
            float dv = __shfl(d, b);
            if (dv < bd[K - 1]) uinsert<K>(dv, it * 64 + b, bd, bi);
        }
    }
}

// ---- kernel: zero hist + accs ----
__global__ void prep0_kernel(int* __restrict__ hist, float* __restrict__ accs) {
    int i = blockIdx.x * blockDim.x + threadIdx.x;
    if (i < 3 * NB) hist[i] = 0;
    if (i < 8) accs[i] = 0.0f;
}

// ---- kernel: histogram of z per set (0=p1,1=p2,2=w) ----
__global__ void count_kernel(const float* __restrict__ coords, const float* __restrict__ gt,
                             const float* __restrict__ flow, int* __restrict__ hist) {
    int i = blockIdx.x * blockDim.x + threadIdx.x;
    if (i >= 3 * N_PTS) return;
    int s = i / N_PTS, j = i - s * N_PTS;
    float z = coords[3 * j + 2];
    if (s == 1) z += gt[3 * j + 2];
    if (s == 2) z += flow[3 * j + 2];
    atomicAdd(&hist[s * NB + zbin(z)], 1);
}

// ---- kernel: exclusive scan per set -> prefix + cursor ----
__global__ __launch_bounds__(256) void scan_kernel(const int* __restrict__ hist,
                                                   int* __restrict__ prefix,
                                                   int* __restrict__ cursor) {
    const int s = blockIdx.x, t = threadIdx.x;
    int v = hist[s * NB + t];
    __shared__ int sd[NB];
    sd[t] = v;
    __syncthreads();
    for (int off = 1; off < NB; off <<= 1) {
        int u = (t >= off) ? sd[t - off] : 0;
        __syncthreads();
        sd[t] += u;
        __syncthreads();
    }
    int excl = sd[t] - v;
    prefix[s * NB + t] = excl;
    cursor[s * NB + t] = excl;
}

// ---- kernel: scatter into z-sorted arrays ----
__global__ void scatter_kernel(const float* __restrict__ coords, const float* __restrict__ gt,
                               const float* __restrict__ flow, int* __restrict__ cursor,
                               float4* __restrict__ p1s, float4* __restrict__ w1s,
                               float4* __restrict__ p2s, float4* __restrict__ wss,
                               int* __restrict__ pos1, int* __restrict__ sidxw) {
    int i = blockIdx.x * blockDim.x + threadIdx.x;
    if (i >= 3 * N_PTS) return;
    int s = i / N_PTS, j = i - s * N_PTS;
    float cx = coords[3 * j + 0], cy = coords[3 * j + 1], cz = coords[3 * j + 2];
    if (s == 0) {
        int pos = atomicAdd(&cursor[zbin(cz)], 1);
        p1s[pos] = make_float4(cx, cy, cz, cx * cx + cy * cy + cz * cz);
        float wx = cx + flow[3 * j + 0], wy = cy + flow[3 * j + 1], wz = cz + flow[3 * j + 2];
        w1s[pos] = make_float4(wx, wy, wz, 0.f);
        pos1[j] = pos;
    } else if (s == 1) {
        float px = cx + gt[3 * j + 0], py = cy + gt[3 * j + 1], pz = cz + gt[3 * j + 2];
        int pos = atomicAdd(&cursor[NB + zbin(pz)], 1);
        p2s[pos] = make_float4(px, py, pz, px * px + py * py + pz * pz);
    } else {
        float wx = cx + flow[3 * j + 0], wy = cy + flow[3 * j + 1], wz = cz + flow[3 * j + 2];
        int pos = atomicAdd(&cursor[2 * NB + zbin(wz)], 1);
        wss[pos] = make_float4(wx, wy, wz, wx * wx + wy * wy + wz * wz);
        sidxw[pos] = j;
    }
}

// ---- kernel: per-chunk conservative z bounds (bin-quantized; exact certs) ----
__global__ void bounds_kernel(const float4* __restrict__ p1s, const float4* __restrict__ p2s,
                              const float4* __restrict__ wss,
                              float* __restrict__ loBnd, float* __restrict__ hiBnd) {
    int i = blockIdx.x * blockDim.x + threadIdx.x;
    if (i >= 3 * NCH) return;
    int s = i / NCH, c = i - s * NCH;
    const float4* base = (s == 0) ? p1s : (s == 1) ? p2s : wss;
    float zf = base[c * 64].z, zl = base[c * 64 + 63].z;
    int bf = zbin(zf), bl = zbin(zl);
    loBnd[i] = (bf == 0) ? -BIGF : (ZMINF + bf * ZW);
    hiBnd[i] = (bl == NB - 1) ? BIGF : (ZMINF + (bl + 1) * ZW);
}

// ---- fused kernel, 4 roles over z-sorted data ----
//  0: curv2 (p2 self-kNN K=10), 1: pc1 self-kNN K=10 (+smooth), 2: rev 1-NN, 3: cross K=5
__global__ __launch_bounds__(256) void fused4_kernel(const float4* __restrict__ p1s,
                                                     const float4* __restrict__ w1s,
                                                     const float4* __restrict__ p2s,
                                                     const float4* __restrict__ wss,
                                                     const int* __restrict__ prefix,
                                                     const float* __restrict__ loBnd,
                                                     const float* __restrict__ hiBnd,
                                                     float* __restrict__ curv2,
                                                     float* __restrict__ mcurv,
                                                     float* __restrict__ crossd,
                                                     int* __restrict__ crossi,
                                                     float* __restrict__ accs) {
    const int role = blockIdx.x / BLKS_PER_PASS;   // contiguous: every XCD sees every role
    const int blk  = blockIdx.x % BLKS_PER_PASS;
    const int tid = threadIdx.x, lane = tid & 63, wv = tid >> 6;
    const int q0 = blk * QPB + wv * QPW;

    if (role == 2) {
        // ---- reverse chamfer: 1-NN of p2 points in w-sorted set ----
        __shared__ float pmn[WPB];
        float nqx[QPW], nqy[QPW], nqz[QPW], qw[QPW], qz[QPW];
#pragma unroll
        for (int qi = 0; qi < QPW; ++qi) {
            float4 t = p2s[q0 + qi];
            nqx[qi] = -2.f * t.x; nqy[qi] = -2.f * t.y; nqz[qi] = -2.f * t.z;
            qw[qi] = t.w; qz[qi] = t.z;
        }
        int c0 = prefix[2 * NB + zbin(qz[0])] >> 6;
        c0 = min(max(c0, 0), NCH - 1);
        const int lo = max(c0 - HW_REV, 0), hi = min(c0 + HW_REV, NCH - 1);
        float mn[QPW];
#pragma unroll
        for (int qi = 0; qi < QPW; ++qi) mn[qi] = BIGF;
        for (int c = lo; c <= hi; ++c) {
            float4 p = wss[(c << 6) + lane];
#pragma unroll
            for (int qi = 0; qi < QPW; ++qi) {
                float d = fmaf(p.x, nqx[qi], fmaf(p.y, nqy[qi], fmaf(p.z, nqz[qi], p.w)));
                mn[qi] = fminf(mn[qi], d);
            }
        }
        float gl = (lo > 0) ? hiBnd[2 * NCH + lo - 1] : -BIGF;
        float gh = (hi < NCH - 1) ? loBnd[2 * NCH + hi + 1] : BIGF;
        float s = 0.f;
#pragma unroll
        for (int qi = 0; qi < QPW; ++qi) {
            float b = mn[qi];
#pragma unroll
            for (int off = 1; off < 64; off <<= 1) b = fminf(b, __shfl_xor(b, off));
            float dk = b + qw[qi];
            bool ok = true;
            if (lo > 0)       { float g = qz[qi] - gl; ok = ok && (g > 0.f) && (dk <= g * g); }
            if (hi < NCH - 1) { float g = gh - qz[qi]; ok = ok && (g > 0.f) && (dk <= g * g); }
            if (!ok) {
                // full exact min
                float m2v = BIGF;
                const float4* cp = wss + lane;
                for (int it = 0; it < N_PTS / 64; ++it) {
                    float4 p = cp[it * 64];
                    float d = fmaf(p.x, nqx[qi], fmaf(p.y, nqy[qi], fmaf(p.z, nqz[qi], p.w)));
                    m2v = fminf(m2v, d);
                }
#pragma unroll
                for (int off = 1; off < 64; off <<= 1) m2v = fminf(m2v, __shfl_xor(m2v, off));
                b = m2v;
            }
            s += b + qw[qi];
        }
        if (lane == 0) pmn[wv] = s;
        __syncthreads();
        if (tid == 0) atomicAdd(&accs[1], pmn[0] + pmn[1] + pmn[2] + pmn[3]);
        return;
    }

    // roles 0/1/3: windowed top-K scan
    const float4* qsrc = (role == 0) ? p2s : (role == 1) ? p1s : wss;
    const float4* cand = (role == 1) ? p1s : p2s;
    const int cset = (role == 1) ? 0 : 1;     // candidate set id for bounds/prefix
    float nqx[QPW], nqy[QPW], nqz[QPW], qx[QPW], qy[QPW], qz[QPW], qw[QPW];
#pragma unroll
    for (int qi = 0; qi < QPW; ++qi) {
        float4 t = qsrc[q0 + qi];
        qx[qi] = t.x; qy[qi] = t.y; qz[qi] = t.z; qw[qi] = t.w;
        nqx[qi] = -2.f * t.x; nqy[qi] = -2.f * t.y; nqz[qi] = -2.f * t.z;
    }
    int c0;
    int HW;
    if (role == 3) { c0 = prefix[cset * NB + zbin(qz[0])] >> 6; HW = HW_CROSS; }
    else           { c0 = q0 >> 6;                              HW = HW_SELF; }
    c0 = min(max(c0, 0), NCH - 1);
    const int lo = max(c0 - HW, 0), hi = min(c0 + HW, NCH - 1);

    float m1[QPW], m2[QPW], m3[QPW]; int i1[QPW], i2[QPW];
#pragma unroll
    for (int qi = 0; qi < QPW; ++qi) { m1[qi] = BIGF; m2[qi] = BIGF; m3[qi] = BIGF; i1[qi] = 0; i2[qi] = 0; }
    for (int c = lo; c <= hi; ++c) {
        const int idx = (c << 6) + lane;
        float4 p = cand[idx];
#pragma unroll
        for (int qi = 0; qi < QPW; ++qi) {
            float d = fmaf(p.x, nqx[qi], fmaf(p.y, nqy[qi], fmaf(p.z, nqz[qi], p.w)));
            bool c1 = d < m1[qi], c2 = d < m2[qi];
            m3[qi] = __builtin_amdgcn_fmed3f(d, m2[qi], m3[qi]);
            m2[qi] = __builtin_amdgcn_fmed3f(d, m1[qi], m2[qi]);
            i2[qi] = c1 ? i1[qi] : (c2 ? idx : i2[qi]);
            m1[qi] = fminf(d, m1[qi]);
            i1[qi] = c1 ? idx : i1[qi];
        }
    }
    const float bLo = (lo > 0) ? hiBnd[cset * NCH + lo - 1] : -BIGF;
    const float bHi = (hi < NCH - 1) ? loBnd[cset * NCH + hi + 1] : BIGF;

    if (role == 3) {
        // ---- cross: K=5, store (true dist, sorted-p2 idx) keyed by sorted-w q ----
        constexpr int K = 5;
#pragma unroll
        for (int qi = 0; qi < QPW; ++qi) {
            float bd[K]; int bi[K];
            merge_pop<K>(m1[qi], m2[qi], m3[qi], i1[qi], i2[qi], bd, bi, lane);
            bool ok = (__ballot(m3[qi] <= bd[K - 1]) == 0ull);
            float dk = bd[K - 1] + qw[qi];
            if (lo > 0)       { float g = qz[qi] - bLo; ok = ok && (g > 0.f) && (dk <= g * g); }
            if (hi < NCH - 1) { float g = bHi - qz[qi]; ok = ok && (g > 0.f) && (dk <= g * g); }
            if (!ok) tau_rescan<K>(p2s, qx[qi], qy[qi], qz[qi], bd[K - 1], bd, bi, lane);
            const int q = q0 + qi;
            if (lane < K) {
                float dv; int iv;
#pragma unroll
                for (int r = 0; r < K; ++r) { if (lane == r) { dv = bd[r]; iv = bi[r]; } }
                crossd[lane * N_PTS + q] = dv + qw[qi];
                crossi[lane * N_PTS + q] = iv;
            }
        }
        return;
    }

    constexpr int K = 10;
    if (role == 0) {
        // ---- curvature of pc2 (sorted order output) ----
#pragma unroll
        for (int qi = 0; qi < QPW; ++qi) {
            float bd[K]; int bi[K];
            merge_pop<K>(m1[qi], m2[qi], m3[qi], i1[qi], i2[qi], bd, bi, lane);
            bool ok = (__ballot(m3[qi] <= bd[K - 1]) == 0ull);
            float dk = bd[K - 1] + qw[qi];
            if (lo > 0)       { float g = qz[qi] - bLo; ok = ok && (g > 0.f) && (dk <= g * g); }
            if (hi < NCH - 1) { float g = bHi - qz[qi]; ok = ok && (g > 0.f) && (dk <= g * g); }
            if (!ok) tau_rescan<K>(p2s, qx[qi], qy[qi], qz[qi], bd[K - 1], bd, bi, lane);
            float ax = 0.f, ay = 0.f, az = 0.f;
#pragma unroll
            for (int r = 0; r < K; ++r) { float4 nb = p2s[bi[r]]; ax += nb.x; ay += nb.y; az += nb.z; }
            if (lane == 0) {
                const int q = q0 + qi;
                curv2[q * 3 + 0] = (ax - 10.f * qx[qi]) * (1.f / 9.f);
                curv2[q * 3 + 1] = (ay - 10.f * qy[qi]) * (1.f / 9.f);
                curv2[q * 3 + 2] = (az - 10.f * qz[qi]) * (1.f / 9.f);
            }
        }
    } else {
        // ---- pc1 self-kNN -> moved_curv (sorted-p1 order) + smoothness ----
        __shared__ float psm[WPB];
        float smsum = 0.f;
#pragma unroll
        for (int qi = 0; qi < QPW; ++qi) {
            float bd[K]; int bi[K];
            merge_pop<K>(m1[qi], m2[qi], m3[qi], i1[qi], i2[qi], bd, bi, lane);
            bool ok = (__ballot(m3[qi] <= bd[K - 1]) == 0ull);
            float dk = bd[K - 1] + qw[qi];
            if (lo > 0)       { float g = qz[qi] - bLo; ok = ok && (g > 0.f) && (dk <= g * g); }
            if (hi < NCH - 1) { float g = bHi - qz[qi]; ok = ok && (g > 0.f) && (dk <= g * g); }
            if (!ok) tau_rescan<K>(p1s, qx[qi], qy[qi], qz[qi], bd[K - 1], bd, bi, lane);
            const int q = q0 + qi;
            float4 wqp = w1s[q];
            const float fqx = wqp.x - qx[qi], fqy = wqp.y - qy[qi], fqz = wqp.z - qz[qi];
            float ax = 0.f, ay = 0.f, az = 0.f, sm = 0.f;
#pragma unroll
            for (int r = 0; r < K; ++r) {
                float4 nw = w1s[bi[r]];
                ax += nw.x; ay += nw.y; az += nw.z;
                if (r < 9) {  // smoothness_k = 9
                    float4 np = p1s[bi[r]];
                    float dx = (nw.x - np.x) - fqx;
                    float dy = (nw.y - np.y) - fqy;
                    float dz = (nw.z - np.z) - fqz;
                    float sq = dx * dx + dy * dy + dz * dz;
                    sm += (sq == 0.f) ? 0.f : sqrtf(sq);
                }
            }
            smsum += sm * 0.125f;  // /8.0 per reference
            if (lane == 0) {
                mcurv[q * 3 + 0] = (ax - 10.f * wqp.x) * (1.f / 9.f);
                mcurv[q * 3 + 1] = (ay - 10.f * wqp.y) * (1.f / 9.f);
                mcurv[q * 3 + 2] = (az - 10.f * wqp.z) * (1.f / 9.f);
            }
        }
        if (lane == 0) psm[wv] = smsum;
        __syncthreads();
        if (tid == 0) atomicAdd(&accs[2], psm[0] + psm[1] + psm[2] + psm[3]);
    }
}

// ---- cross epilogue: sorted-w thread-per-query IDW + chamfer1/curv sums ----
__global__ __launch_bounds__(256) void epi_kernel(const float* __restrict__ crossd,
                                                  const int* __restrict__ crossi,
                                                  const float* __restrict__ curv2,
                                                  const float* __restrict__ mcurv,
                                                  const int* __restrict__ sidxw,
                                                  const int* __restrict__ pos1,
                                                  float* __restrict__ accs) {
    __shared__ float pd1[WPB], pcv[WPB];
    const int tid = threadIdx.x, lane = tid & 63, wv = tid >> 6;
    const int q = blockIdx.x * 256 + tid;
    constexpr int K = 5;
    float bd[K]; int bi[K];
#pragma unroll
    for (int r = 0; r < K; ++r) { bd[r] = crossd[r * N_PTS + q]; bi[r] = crossi[r * N_PTS + q]; }
    float w[K], wsum = 0.f;
#pragma unroll
    for (int r = 0; r < K; ++r) { w[r] = 1.f / (bd[r] + 1e-8f); wsum += w[r]; }
    float ix = 0.f, iy = 0.f, iz = 0.f;
#pragma unroll
    for (int r = 0; r < K; ++r) {
        float ww = w[r] / wsum;
        ix += ww * curv2[bi[r] * 3 + 0];
        iy += ww * curv2[bi[r] * 3 + 1];
        iz += ww * curv2[bi[r] * 3 + 2];
    }
    const int mq = pos1[sidxw[q]];   // same original point in sorted-p1 order
    float dx = ix - mcurv[mq * 3 + 0];
    float dy = iy - mcurv[mq * 3 + 1];
    float dz = iz - mcurv[mq * 3 + 2];
    float d1 = bd[0];
    float cv = dx * dx + dy * dy + dz * dz;
#pragma unroll
    for (int off = 1; off < 64; off <<= 1) {
        d1 += __shfl_xor(d1, off);
        cv += __shfl_xor(cv, off);
    }
    if (lane == 0) { pd1[wv] = d1; pcv[wv] = cv; }
    __syncthreads();
    if (tid == 0) {
        atomicAdd(&accs[0], pd1[0] + pd1[1] + pd1[2] + pd1[3]);
        atomicAdd(&accs[3], pcv[0] + pcv[1] + pcv[2] + pcv[3]);
    }
}

// ---- finalize ----
__global__ void fin_kernel(const float* __restrict__ accs, float* __restrict__ out) {
    if (threadIdx.x == 0 && blockIdx.x == 0)
        out[0] = W_CHAM * (accs[0] + accs[1]) + W_CURV * accs[3] + W_SMOO * accs[2];
}

extern "C" void kernel_launch(void* const* d_in, const int* in_sizes, int n_in,
                              void* d_out, int out_size, void* d_ws, size_t ws_size,
                              hipStream_t stream) {
    const float* flow   = (const float*)d_in[0];  // registration_pred (1,N,3)
    const float* gt     = (const float*)d_in[1];  // registration_gt   (1,N,3)
    const float* coords = (const float*)d_in[2];  // (N,3)
    // d_in[3] = smoothness_k (=9), folded as constant (reference fixed /8.0 anyway)

    char* w = (char*)d_ws;
    float4* p1s   = (float4*)w;                 w += N_PTS * 16;
    float4* w1s   = (float4*)w;                 w += N_PTS * 16;
    float4* p2s   = (float4*)w;                 w += N_PTS * 16;
    float4* wss   = (float4*)w;                 w += N_PTS * 16;
    float*  curv2 = (float*)w;                  w += N_PTS * 12;
    float*  mcurv = (float*)w;                  w += N_PTS * 12;
    float*  crossd = (float*)w;                 w += N_PTS * 20;
    int*    crossi = (int*)w;                   w += N_PTS * 20;
    int*    pos1   = (int*)w;                   w += N_PTS * 4;
    int*    sidxw  = (int*)w;                   w += N_PTS * 4;
    int*    hist   = (int*)w;                   w += 3 * NB * 4;
    int*    prefix = (int*)w;                   w += 3 * NB * 4;
    int*    cursor = (int*)w;                   w += 3 * NB * 4;
    float*  loBnd  = (float*)w;                 w += 3 * NCH * 4;
    float*  hiBnd  = (float*)w;                 w += 3 * NCH * 4;
    float*  accs   = (float*)w;
    float*  out    = (float*)d_out;

    prep0_kernel<<<4, 256, 0, stream>>>(hist, accs);
    count_kernel<<<(3 * N_PTS + 255) / 256, 256, 0, stream>>>(coords, gt, flow, hist);
    scan_kernel<<<3, NB, 0, stream>>>(hist, prefix, cursor);
    scatter_kernel<<<(3 * N_PTS + 255) / 256, 256, 0, stream>>>(coords, gt, flow, cursor,
                                                                p1s, w1s, p2s, wss, pos1, sidxw);
    bounds_kernel<<<(3 * NCH + 255) / 256, 256, 0, stream>>>(p1s, p2s, wss, loBnd, hiBnd);
    fused4_kernel<<<4 * BLKS_PER_PASS, 256, 0, stream>>>(p1s, w1s, p2s, wss, prefix,
                                                         loBnd, hiBnd, curv2, mcurv,
                                                         crossd, crossi, accs);
    epi_kernel<<<N_PTS / 256, 256, 0, stream>>>(crossd, crossi, curv2, mcurv, sidxw, pos1, accs);
    fin_kernel<<<1, 64, 0, stream>>>(accs, out);
}

// Round 12
// 330.720 us; speedup vs baseline: 1.7273x; 1.7273x over previous
//
#include <hip/hip_runtime.h>
#include <hip/hip_bf16.h>
#include <math.h>

#define N_PTS 8192
#define QPW 4                 // queries per wave
#define WPB 4                 // waves per block
#define QPB (QPW * WPB)       // 16 queries per block
#define BLKS_PER_ROLE (N_PTS / QPB)   // 512

#define NB 256                // z bins (counting sort)
#define NCH 128               // chunks of 64 per set
#define ZMINF (-6.0f)
#define ZW 0.046875f          // 12/256
#define INV_ZW (1.0f / ZW)

#define SPAN_SELF 27          // window chunks for K=10 self-kNN
#define SPAN_CROSS 23         // for K=5 cross
#define SPAN_REV 15           // for 1-NN reverse chamfer

// F_CHAMFER*ALPHA0 = 0.02, F_CURVATURE*ALPHA0 = 0.006, F_SMOOTH*ALPHA0 = 0.01
#define W_CHAM 0.02f
#define W_CURV 0.006f
#define W_SMOO 0.01f
#define BIGF 1e30f

__device__ __forceinline__ int zbin(float z) {
    int b = (int)floorf((z - ZMINF) * INV_ZW);
    return min(max(b, 0), NB - 1);
}

// ---- wave-uniform sorted insert (tau_rescan only; proven R6-R10) ----
template <int K>
__device__ __forceinline__ void uinsert(float d, int idx, float (&bd)[K], int (&bi)[K]) {
    bd[K - 1] = d; bi[K - 1] = idx;
#pragma unroll
    for (int s = K - 1; s > 0; --s) {
        bool sw = bd[s] < bd[s - 1];
        float td = sw ? bd[s - 1] : bd[s];
        bd[s - 1] = sw ? bd[s] : bd[s - 1];
        bd[s] = td;
        int ti = sw ? bi[s - 1] : bi[s];
        bi[s - 1] = sw ? bi[s] : bi[s - 1];
        bi[s] = ti;
    }
}

// ---- merge 64 per-lane sorted lists {(m1,i1),(m2,i2),(m3,-)} -> top-K (proven) ----
template <int K>
__device__ __forceinline__ void merge_pop(float m1, float m2, float m3, int i1, int i2,
                                          float (&bd)[K], int (&bi)[K], int lane) {
    float h0 = m1, h1 = m2, h2 = m3;
    int   j0 = i1, j1 = i2;
#pragma unroll
    for (int r = 0; r < K; ++r) {
        float bv = h0;
#pragma unroll
        for (int off = 1; off < 64; off <<= 1) bv = fminf(bv, __shfl_xor(bv, off));
        unsigned long long eq = __ballot(h0 == bv);
        int wl = (int)__builtin_ctzll(eq);
        bd[r] = bv; bi[r] = __shfl(j0, wl);
        if (lane == wl) { h0 = h1; j0 = j1; h1 = h2; j1 = -1; h2 = BIGF; }
    }
}

// ---- exact fixed-tau FULL rescan (shifted domain; proven) ----
template <int K>
__device__ void tau_rescan(const float4* __restrict__ cand,
                           float qx, float qy, float qz, float tau,
                           float (&bd)[K], int (&bi)[K], int lane) {
#pragma unroll
    for (int r = 0; r < K; ++r) { bd[r] = BIGF; bi[r] = 0; }
    const float4* cp = cand + lane;
    for (int it = 0; it < N_PTS / 64; ++it) {
        float4 p = cp[it * 64];
        float dot = fmaf(p.x, qx, fmaf(p.y, qy, p.z * qz));
        float d = fmaf(-2.f, dot, p.w);
        unsigned long long m = __ballot(d <= tau);
        while (m) {
            int b = __builtin_ctzll(m);
            m &= m - 1;
            float dv = __shfl(d, b);
            if (dv < bd[K - 1]) uinsert<K>(dv, it * 64 + b, bd, bi);
        }
    }
}

// ---- proven R10 full-scan path (QPW=1): scan + merge + m3-cert + tau_rescan ----
template <int K>
__device__ void full_exact(const float4* __restrict__ qarr, const float4* __restrict__ cand,
                           int q, int lane, float (&bd)[K], int (&bi)[K]) {
    float4 t = qarr[q];
    const float nqx = -2.f * t.x, nqy = -2.f * t.y, nqz = -2.f * t.z;
    float m1 = BIGF, m2 = BIGF, m3 = BIGF; int i1 = 0, i2 = 0;
    const float4* cp = cand + lane;
#pragma unroll 4
    for (int it = 0; it < N_PTS / 64; ++it) {
        float4 p = cp[it * 64];
        const int idx = it * 64 + lane;
        float d = fmaf(p.x, nqx, fmaf(p.y, nqy, fmaf(p.z, nqz, p.w)));
        bool c1 = d < m1, c2 = d < m2;
        m3 = __builtin_amdgcn_fmed3f(d, m2, m3);
        m2 = __builtin_amdgcn_fmed3f(d, m1, m2);
        i2 = c1 ? i1 : (c2 ? idx : i2);
        m1 = fminf(d, m1);
        i1 = c1 ? idx : i1;
    }
    merge_pop<K>(m1, m2, m3, i1, i2, bd, bi, lane);
    if (__ballot(m3 <= bd[K - 1]) != 0ull)
        tau_rescan<K>(cand, t.x, t.y, t.z, bd[K - 1], bd, bi, lane);
}

// ---- sort preprocessing ----
__global__ void prep0_kernel(int* __restrict__ hist, int* __restrict__ retryq,
                             float* __restrict__ accs) {
    int i = blockIdx.x * blockDim.x + threadIdx.x;
    if (i < 3 * NB) hist[i] = 0;
    if (i < 8) accs[i] = 0.0f;
    if (i < 2) retryq[i] = 0;
}

__global__ void count_kernel(const float* __restrict__ coords, const float* __restrict__ gt,
                             const float* __restrict__ flow, int* __restrict__ hist) {
    int i = blockIdx.x * blockDim.x + threadIdx.x;
    if (i >= 3 * N_PTS) return;
    int s = i / N_PTS, j = i - s * N_PTS;
    float z = coords[3 * j + 2];
    if (s == 1) z += gt[3 * j + 2];
    if (s == 2) z += flow[3 * j + 2];
    atomicAdd(&hist[s * NB + zbin(z)], 1);
}

__global__ __launch_bounds__(256) void scan_kernel(const int* __restrict__ hist,
                                                   int* __restrict__ prefix,
                                                   int* __restrict__ cursor) {
    const int s = blockIdx.x, t = threadIdx.x;
    int v = hist[s * NB + t];
    __shared__ int sd[NB];
    sd[t] = v;
    __syncthreads();
    for (int off = 1; off < NB; off <<= 1) {
        int u = (t >= off) ? sd[t - off] : 0;
        __syncthreads();
        sd[t] += u;
        __syncthreads();
    }
    int excl = sd[t] - v;
    prefix[s * NB + t] = excl;
    cursor[s * NB + t] = excl;
}

__global__ void scatter_kernel(const float* __restrict__ coords, const float* __restrict__ gt,
                               const float* __restrict__ flow, int* __restrict__ cursor,
                               float4* __restrict__ p1s, float4* __restrict__ w1s,
                               float4* __restrict__ p2s, float4* __restrict__ wss,
                               int* __restrict__ pos1, int* __restrict__ sidxw) {
    int i = blockIdx.x * blockDim.x + threadIdx.x;
    if (i >= 3 * N_PTS) return;
    int s = i / N_PTS, j = i - s * N_PTS;
    float cx = coords[3 * j + 0], cy = coords[3 * j + 1], cz = coords[3 * j + 2];
    if (s == 0) {
        int pos = atomicAdd(&cursor[zbin(cz)], 1);
        p1s[pos] = make_float4(cx, cy, cz, cx * cx + cy * cy + cz * cz);
        float wx = cx + flow[3 * j + 0], wy = cy + flow[3 * j + 1], wz = cz + flow[3 * j + 2];
        w1s[pos] = make_float4(wx, wy, wz, 0.f);
        pos1[j] = pos;
    } else if (s == 1) {
        float px = cx + gt[3 * j + 0], py = cy + gt[3 * j + 1], pz = cz + gt[3 * j + 2];
        int pos = atomicAdd(&cursor[NB + zbin(pz)], 1);
        p2s[pos] = make_float4(px, py, pz, px * px + py * py + pz * pz);
    } else {
        float wx = cx + flow[3 * j + 0], wy = cy + flow[3 * j + 1], wz = cz + flow[3 * j + 2];
        int pos = atomicAdd(&cursor[2 * NB + zbin(wz)], 1);
        wss[pos] = make_float4(wx, wy, wz, wx * wx + wy * wy + wz * wz);
        sidxw[pos] = j;
    }
}

// per-chunk conservative z bounds (bin-quantized; monotone because bin-sorted)
__global__ void bounds_kernel(const float4* __restrict__ p1s, const float4* __restrict__ p2s,
                              const float4* __restrict__ wss,
                              float* __restrict__ loBnd, float* __restrict__ hiBnd) {
    int i = blockIdx.x * blockDim.x + threadIdx.x;
    if (i >= 3 * NCH) return;
    int s = i / NCH, c = i - s * NCH;
    const float4* base = (s == 0) ? p1s : (s == 1) ? p2s : wss;
    int bf = zbin(base[c * 64].z), bl = zbin(base[c * 64 + 63].z);
    loBnd[i] = (bf == 0) ? -BIGF : (ZMINF + bf * ZW);
    hiBnd[i] = (bl == NB - 1) ? BIGF : (ZMINF + (bl + 1) * ZW);
}

// ---- windowed scan role: scan SPAN chunks, merge, certify, store; queue fails ----
template <int K, int SPAN, bool STORE_D>
__device__ void role_scan(const float4* __restrict__ qarr, const float4* __restrict__ cand,
                          int cset, bool useprefix,
                          const int* __restrict__ prefix,
                          const float* __restrict__ loBnd, const float* __restrict__ hiBnd,
                          int q0, int lane, int roleTag,
                          float* __restrict__ outd, unsigned short* __restrict__ outi,
                          int* __restrict__ retryq) {
    float nqx[QPW], nqy[QPW], nqz[QPW], qz[QPW], qw[QPW];
#pragma unroll
    for (int qi = 0; qi < QPW; ++qi) {
        float4 t = qarr[q0 + qi];
        nqx[qi] = -2.f * t.x; nqy[qi] = -2.f * t.y; nqz[qi] = -2.f * t.z;
        qz[qi] = t.z; qw[qi] = t.w;
    }
    int c0 = useprefix ? (prefix[cset * NB + zbin(qz[0])] >> 6) : (q0 >> 6);
    int s0 = min(max(c0 - SPAN / 2, 0), NCH - SPAN);
    float m1[QPW], m2[QPW], m3[QPW]; int i1[QPW], i2[QPW];
#pragma unroll
    for (int qi = 0; qi < QPW; ++qi) { m1[qi] = BIGF; m2[qi] = BIGF; m3[qi] = BIGF; i1[qi] = 0; i2[qi] = 0; }
#pragma unroll 3
    for (int j = 0; j < SPAN; ++j) {
        const int idx = ((s0 + j) << 6) + lane;
        float4 p = cand[idx];
#pragma unroll
        for (int qi = 0; qi < QPW; ++qi) {
            float d = fmaf(p.x, nqx[qi], fmaf(p.y, nqy[qi], fmaf(p.z, nqz[qi], p.w)));
            bool c1 = d < m1[qi], c2 = d < m2[qi];
            m3[qi] = __builtin_amdgcn_fmed3f(d, m2[qi], m3[qi]);
            m2[qi] = __builtin_amdgcn_fmed3f(d, m1[qi], m2[qi]);
            i2[qi] = c1 ? i1[qi] : (c2 ? idx : i2[qi]);
            m1[qi] = fminf(d, m1[qi]);
            i1[qi] = c1 ? idx : i1[qi];
        }
    }
    const int lo = s0, hi = s0 + SPAN - 1;
    const float bLo = (lo > 0) ? hiBnd[cset * NCH + lo - 1] : -BIGF;
    const float bHi = (hi < NCH - 1) ? loBnd[cset * NCH + hi + 1] : BIGF;
#pragma unroll
    for (int qi = 0; qi < QPW; ++qi) {
        float bd[K]; int bi[K];
        merge_pop<K>(m1[qi], m2[qi], m3[qi], i1[qi], i2[qi], bd, bi, lane);
        bool ok = (__ballot(m3[qi] <= bd[K - 1]) == 0ull);  // lane-completeness cert
        float dk = bd[K - 1] + qw[qi];                      // true kth dist^2 (upper bd)
        if (lo > 0)       { float g = qz[qi] - bLo; ok = ok && (g > 0.f) && (dk <= g * g); }
        if (hi < NCH - 1) { float g = bHi - qz[qi]; ok = ok && (g > 0.f) && (dk <= g * g); }
        const int q = q0 + qi;
        if (!ok && lane == 0) { int e = atomicAdd(&retryq[0], 1); retryq[2 + e] = (roleTag << 16) | q; }
        if (lane < K) {
            float dv = 0.f; int iv = 0;
#pragma unroll
            for (int r = 0; r < K; ++r) if (lane == r) { dv = bd[r]; iv = bi[r]; }
            if (STORE_D) outd[lane * N_PTS + q] = dv + qw[qi];  // true sq dist
            outi[lane * N_PTS + q] = (unsigned short)iv;
        }
    }
}

// ---- fused kernel: 4 roles, contiguous role mapping (R10 lesson) ----
__global__ __launch_bounds__(256) void fused_kernel(const float4* __restrict__ p1s,
                                                    const float4* __restrict__ w1s,
                                                    const float4* __restrict__ p2s,
                                                    const float4* __restrict__ wss,
                                                    const int* __restrict__ prefix,
                                                    const float* __restrict__ loBnd,
                                                    const float* __restrict__ hiBnd,
                                                    unsigned short* __restrict__ i10a,
                                                    unsigned short* __restrict__ i10b,
                                                    float* __restrict__ knn5d,
                                                    unsigned short* __restrict__ knn5i,
                                                    int* __restrict__ retryq,
                                                    float* __restrict__ accs) {
    const int role = blockIdx.x / BLKS_PER_ROLE;
    const int blk  = blockIdx.x % BLKS_PER_ROLE;
    const int tid = threadIdx.x, lane = tid & 63, wv = tid >> 6;
    const int q0 = blk * QPB + wv * QPW;

    if (role == 0) {
        role_scan<10, SPAN_SELF, false>(p2s, p2s, 1, false, prefix, loBnd, hiBnd,
                                        q0, lane, 0, nullptr, i10a, retryq);
    } else if (role == 1) {
        role_scan<10, SPAN_SELF, false>(p1s, p1s, 0, false, prefix, loBnd, hiBnd,
                                        q0, lane, 1, nullptr, i10b, retryq);
    } else if (role == 3) {
        role_scan<5, SPAN_CROSS, true>(wss, p2s, 1, true, prefix, loBnd, hiBnd,
                                       q0, lane, 3, knn5d, knn5i, retryq);
    } else {
        // ---- reverse chamfer: windowed 1-NN of p2 in w; inline cheap fallback ----
        __shared__ float pmn[WPB];
        float nqx[QPW], nqy[QPW], nqz[QPW], qz[QPW], qw[QPW];
#pragma unroll
        for (int qi = 0; qi < QPW; ++qi) {
            float4 t = p2s[q0 + qi];
            nqx[qi] = -2.f * t.x; nqy[qi] = -2.f * t.y; nqz[qi] = -2.f * t.z;
            qz[qi] = t.z; qw[qi] = t.w;
        }
        int c0 = prefix[2 * NB + zbin(qz[0])] >> 6;
        int s0 = min(max(c0 - SPAN_REV / 2, 0), NCH - SPAN_REV);
        float mn[QPW];
#pragma unroll
        for (int qi = 0; qi < QPW; ++qi) mn[qi] = BIGF;
#pragma unroll 3
        for (int j = 0; j < SPAN_REV; ++j) {
            float4 p = wss[((s0 + j) << 6) + lane];
#pragma unroll
            for (int qi = 0; qi < QPW; ++qi) {
                float d = fmaf(p.x, nqx[qi], fmaf(p.y, nqy[qi], fmaf(p.z, nqz[qi], p.w)));
                mn[qi] = fminf(mn[qi], d);
            }
        }
        const int lo = s0, hi = s0 + SPAN_REV - 1;
        const float bLo = (lo > 0) ? hiBnd[2 * NCH + lo - 1] : -BIGF;
        const float bHi = (hi < NCH - 1) ? loBnd[2 * NCH + hi + 1] : BIGF;
        float s = 0.f;
#pragma unroll
        for (int qi = 0; qi < QPW; ++qi) {
            float b = mn[qi];
#pragma unroll
            for (int off = 1; off < 64; off <<= 1) b = fminf(b, __shfl_xor(b, off));
            float dk = b + qw[qi];
            bool ok = true;
            if (lo > 0)       { float g = qz[qi] - bLo; ok = ok && (g > 0.f) && (dk <= g * g); }
            if (hi < NCH - 1) { float g = bHi - qz[qi]; ok = ok && (g > 0.f) && (dk <= g * g); }
            if (!ok) {  // rare: exact full min (wave-uniform branch)
                float mv = BIGF;
                const float4* cp = wss + lane;
                for (int it = 0; it < N_PTS / 64; ++it) {
                    float4 p = cp[it * 64];
                    float d = fmaf(p.x, nqx[qi], fmaf(p.y, nqy[qi], fmaf(p.z, nqz[qi], p.w)));
                    mv = fminf(mv, d);
                }
#pragma unroll
                for (int off = 1; off < 64; off <<= 1) mv = fminf(mv, __shfl_xor(mv, off));
                b = mv;
            }
            s += b + qw[qi];
        }
        if (lane == 0) pmn[wv] = s;
        __syncthreads();
        if (tid == 0) atomicAdd(&accs[1], pmn[0] + pmn[1] + pmn[2] + pmn[3]);
    }
}

// ---- retry: re-run failed queries through the PROVEN full-scan path ----
__global__ __launch_bounds__(256) void retry_kernel(const float4* __restrict__ p1s,
                                                    const float4* __restrict__ p2s,
                                                    const float4* __restrict__ wss,
                                                    unsigned short* __restrict__ i10a,
                                                    unsigned short* __restrict__ i10b,
                                                    float* __restrict__ knn5d,
                                                    unsigned short* __restrict__ knn5i,
                                                    const int* __restrict__ retryq) {
    const int lane = threadIdx.x & 63;
    const int w = blockIdx.x * WPB + (threadIdx.x >> 6);
    const int n = retryq[0];
    for (int e = w; e < n; e += 256 * WPB) {
        int ent = retryq[2 + e];
        int role = ent >> 16, q = ent & 0xFFFF;
        if (role == 3) {
            float bd[5]; int bi[5];
            full_exact<5>(wss, p2s, q, lane, bd, bi);
            float qw = wss[q].w;
            if (lane < 5) {
                float dv = 0.f; int iv = 0;
#pragma unroll
                for (int r = 0; r < 5; ++r) if (lane == r) { dv = bd[r]; iv = bi[r]; }
                knn5d[lane * N_PTS + q] = dv + qw;
                knn5i[lane * N_PTS + q] = (unsigned short)iv;
            }
        } else {
            float bd[10]; int bi[10];
            const float4* arr = (role == 0) ? p2s : p1s;
            full_exact<10>(arr, arr, q, lane, bd, bi);
            unsigned short* out = (role == 0) ? i10a : i10b;
            if (lane < 10) {
                int iv = 0;
#pragma unroll
                for (int r = 0; r < 10; ++r) if (lane == r) iv = bi[r];
                out[lane * N_PTS + q] = (unsigned short)iv;
            }
        }
    }
}

// ---- epilogue A: curvature(pc2), moved-curvature + smoothness ----
__global__ __launch_bounds__(256) void epiA_kernel(const float4* __restrict__ p1s,
                                                   const float4* __restrict__ w1s,
                                                   const float4* __restrict__ p2s,
                                                   const unsigned short* __restrict__ i10a,
                                                   const unsigned short* __restrict__ i10b,
                                                   const int* __restrict__ ksm_p,
                                                   float* __restrict__ curv2,
                                                   float* __restrict__ mcurv,
                                                   float* __restrict__ accs) {
    __shared__ float psm[WPB];
    const int t = blockIdx.x * 256 + threadIdx.x;
    const int lane = threadIdx.x & 63, wv = threadIdx.x >> 6;
    const int ksm = ksm_p[0];  // 9
    // curv2 (sorted-p2 order)
    float4 q2 = p2s[t];
    float ax = 0.f, ay = 0.f, az = 0.f;
#pragma unroll
    for (int r = 0; r < 10; ++r) {
        float4 nb = p2s[i10a[r * N_PTS + t]];
        ax += nb.x; ay += nb.y; az += nb.z;
    }
    curv2[t * 3 + 0] = (ax - 10.f * q2.x) * (1.f / 9.f);
    curv2[t * 3 + 1] = (ay - 10.f * q2.y) * (1.f / 9.f);
    curv2[t * 3 + 2] = (az - 10.f * q2.z) * (1.f / 9.f);
    // moved curvature + smoothness (sorted-p1 order)
    float4 qw1 = w1s[t], qp1 = p1s[t];
    float fqx = qw1.x - qp1.x, fqy = qw1.y - qp1.y, fqz = qw1.z - qp1.z;
    ax = ay = az = 0.f;
    float sm = 0.f;
#pragma unroll
    for (int r = 0; r < 10; ++r) {
        int i = i10b[r * N_PTS + t];
        float4 nw = w1s[i];
        ax += nw.x; ay += nw.y; az += nw.z;
        if (r < ksm) {
            float4 np = p1s[i];
            float dx = (nw.x - np.x) - fqx;
            float dy = (nw.y - np.y) - fqy;
            float dz = (nw.z - np.z) - fqz;
            float sq = dx * dx + dy * dy + dz * dz;
            sm += (sq == 0.f) ? 0.f : sqrtf(sq);
        }
    }
    mcurv[t * 3 + 0] = (ax - 10.f * qw1.x) * (1.f / 9.f);
    mcurv[t * 3 + 1] = (ay - 10.f * qw1.y) * (1.f / 9.f);
    mcurv[t * 3 + 2] = (az - 10.f * qw1.z) * (1.f / 9.f);
    sm *= 0.125f;
#pragma unroll
    for (int off = 1; off < 64; off <<= 1) sm += __shfl_xor(sm, off);
    if (lane == 0) psm[wv] = sm;
    __syncthreads();
    if (threadIdx.x == 0) atomicAdd(&accs[2], psm[0] + psm[1] + psm[2] + psm[3]);
}

// ---- epilogue B: IDW interp + chamfer1 + curvature-loss sums ----
__global__ __launch_bounds__(256) void epiB_kernel(const float* __restrict__ knn5d,
                                                   const unsigned short* __restrict__ knn5i,
                                                   const float* __restrict__ curv2,
                                                   const float* __restrict__ mcurv,
                                                   const int* __restrict__ pos1,
                                                   const int* __restrict__ sidxw,
                                                   float* __restrict__ accs) {
    __shared__ float pd1[WPB], pcv[WPB];
    const int t = blockIdx.x * 256 + threadIdx.x;
    const int lane = threadIdx.x & 63, wv = threadIdx.x >> 6;
    float bd[5]; int bi[5];
#pragma unroll
    for (int r = 0; r < 5; ++r) { bd[r] = knn5d[r * N_PTS + t]; bi[r] = knn5i[r * N_PTS + t]; }
    float w[5], wsum = 0.f;
#pragma unroll
    for (int r = 0; r < 5; ++r) { w[r] = 1.f / (bd[r] + 1e-8f); wsum += w[r]; }
    float ix = 0.f, iy = 0.f, iz = 0.f;
#pragma unroll
    for (int r = 0; r < 5; ++r) {
        float ww = w[r] / wsum;
        ix += ww * curv2[bi[r] * 3 + 0];
        iy += ww * curv2[bi[r] * 3 + 1];
        iz += ww * curv2[bi[r] * 3 + 2];
    }
    const int mq = pos1[sidxw[t]];   // sorted-w -> original -> sorted-p1
    float dx = ix - mcurv[mq * 3 + 0];
    float dy = iy - mcurv[mq * 3 + 1];
    float dz = iz - mcurv[mq * 3 + 2];
    float d1 = bd[0];
    float cv = dx * dx + dy * dy + dz * dz;
#pragma unroll
    for (int off = 1; off < 64; off <<= 1) { d1 += __shfl_xor(d1, off); cv += __shfl_xor(cv, off); }
    if (lane == 0) { pd1[wv] = d1; pcv[wv] = cv; }
    __syncthreads();
    if (threadIdx.x == 0) {
        atomicAdd(&accs[0], pd1[0] + pd1[1] + pd1[2] + pd1[3]);
        atomicAdd(&accs[3], pcv[0] + pcv[1] + pcv[2] + pcv[3]);
    }
}

__global__ void fin_kernel(const float* __restrict__ accs, float* __restrict__ out) {
    if (threadIdx.x == 0 && blockIdx.x == 0)
        out[0] = W_CHAM * (accs[0] + accs[1]) + W_CURV * accs[3] + W_SMOO * accs[2];
}

extern "C" void kernel_launch(void* const* d_in, const int* in_sizes, int n_in,
                              void* d_out, int out_size, void* d_ws, size_t ws_size,
                              hipStream_t stream) {
    const float* flow   = (const float*)d_in[0];
    const float* gt     = (const float*)d_in[1];
    const float* coords = (const float*)d_in[2];
    const int*   ksm    = (const int*)d_in[3];

    char* w = (char*)d_ws;
    float4* p1s   = (float4*)w;              w += N_PTS * 16;
    float4* w1s   = (float4*)w;              w += N_PTS * 16;
    float4* p2s   = (float4*)w;              w += N_PTS * 16;
    float4* wss   = (float4*)w;              w += N_PTS * 16;
    float*  curv2 = (float*)w;               w += N_PTS * 12;
    float*  mcurv = (float*)w;               w += N_PTS * 12;
    float*  knn5d = (float*)w;               w += N_PTS * 20;
    float*  loBnd = (float*)w;               w += 3 * NCH * 4;
    float*  hiBnd = (float*)w;               w += 3 * NCH * 4;
    int*    pos1  = (int*)w;                 w += N_PTS * 4;
    int*    sidxw = (int*)w;                 w += N_PTS * 4;
    int*    hist  = (int*)w;                 w += 3 * NB * 4;
    int*    prefix= (int*)w;                 w += 3 * NB * 4;
    int*    cursor= (int*)w;                 w += 3 * NB * 4;
    int*    retryq= (int*)w;                 w += (2 + 3 * N_PTS) * 4;
    unsigned short* i10a = (unsigned short*)w; w += 10 * N_PTS * 2;
    unsigned short* i10b = (unsigned short*)w; w += 10 * N_PTS * 2;
    unsigned short* knn5i= (unsigned short*)w; w += 5 * N_PTS * 2;
    float*  accs  = (float*)w;
    float*  out   = (float*)d_out;

    prep0_kernel<<<4, 256, 0, stream>>>(hist, retryq, accs);
    count_kernel<<<(3 * N_PTS + 255) / 256, 256, 0, stream>>>(coords, gt, flow, hist);
    scan_kernel<<<3, NB, 0, stream>>>(hist, prefix, cursor);
    scatter_kernel<<<(3 * N_PTS + 255) / 256, 256, 0, stream>>>(coords, gt, flow, cursor,
                                                                p1s, w1s, p2s, wss, pos1, sidxw);
    bounds_kernel<<<(3 * NCH + 255) / 256, 256, 0, stream>>>(p1s, p2s, wss, loBnd, hiBnd);
    fused_kernel<<<4 * BLKS_PER_ROLE, 256, 0, stream>>>(p1s, w1s, p2s, wss, prefix,
                                                        loBnd, hiBnd, i10a, i10b,
                                                        knn5d, knn5i, retryq, accs);
    retry_kernel<<<256, 256, 0, stream>>>(p1s, p2s, wss, i10a, i10b, knn5d, knn5i, retryq);
    epiA_kernel<<<N_PTS / 256, 256, 0, stream>>>(p1s, w1s, p2s, i10a, i10b, ksm,
                                                 curv2, mcurv, accs);
    epiB_kernel<<<N_PTS / 256, 256, 0, stream>>>(knn5d, knn5i, curv2, mcurv, pos1, sidxw, accs);
    fin_kernel<<<1, 64, 0, stream>>>(accs, out);
}